// Round 11
// baseline (674.783 us; speedup 1.0000x reference)
//
#include <hip/hip_runtime.h>
#include <stdint.h>

#define N_NODES 20000
#define N_EDGES 320000
#define N_BATCH 32
#define DIM     128

typedef _Float16 v8h __attribute__((ext_vector_type(8)));
typedef float v4f __attribute__((ext_vector_type(4)));

static inline int cdiv(int a, int b){ return (a + b - 1) / b; }

// pack two f32 -> two f16 (RTZ), single v_cvt_pkrtz_f16_f32 (GCN-era instr)
__device__ __forceinline__ uint32_t pk_f16(float lo, float hi){
  auto h = __builtin_amdgcn_cvt_pkrtz(lo, hi);   // __fp16 ext_vector(2)
  return __builtin_bit_cast(uint32_t, h);
}
// acc += f32(f16 from lo/hi half of u) * w  -- single v_fma_mix_f32 (gfx906+)
__device__ __forceinline__ void fmix_lo(float& acc, uint32_t u, float w){
  asm("v_fma_mix_f32 %0, %1, %2, %0 op_sel:[0,0,0] op_sel_hi:[1,0,0]"
      : "+v"(acc) : "v"(u), "v"(w));
}
__device__ __forceinline__ void fmix_hi(float& acc, uint32_t u, float w){
  asm("v_fma_mix_f32 %0, %1, %2, %0 op_sel:[1,0,0] op_sel_hi:[1,0,0]"
      : "+v"(acc) : "v"(u), "v"(w));
}

// ---------------- setup kernels ----------------

__global__ void k_zero(uint32_t* p, int n){
  int i = blockIdx.x * 256 + threadIdx.x;
  if (i < n) p[i] = 0u;
}

__global__ void k_hist(const int* __restrict__ ei, uint32_t* __restrict__ hist){
  int e = blockIdx.x * 256 + threadIdx.x;
  if (e < N_EDGES){
    int d = ei[N_EDGES + e];
    atomicAdd(&hist[d], 1u);
  }
}

// single-block exclusive scan of hist -> row_start; also deg-derived dinv, c-init
__global__ void k_scan(const uint32_t* __restrict__ hist, uint32_t* __restrict__ row_start,
                       float* __restrict__ dinv, float* __restrict__ cw){
  __shared__ uint32_t part[1024];
  const int t = threadIdx.x;
  const int base = t * 20;                       // 1024*20 = 20480 >= 20000
  uint32_t cnt[20];
  uint32_t s = 0;
  #pragma unroll
  for (int i = 0; i < 20; i++){
    int idx = base + i;
    uint32_t v = (idx < N_NODES) ? hist[idx] : 0u;
    cnt[i] = v; s += v;
  }
  part[t] = s;
  __syncthreads();
  for (int off = 1; off < 1024; off <<= 1){      // inclusive Hillis-Steele
    uint32_t v = part[t];
    uint32_t add = (t >= off) ? part[t - off] : 0u;
    __syncthreads();
    part[t] = v + add;
    __syncthreads();
  }
  uint32_t run = (t > 0) ? part[t - 1] : 0u;     // exclusive prefix
  #pragma unroll
  for (int i = 0; i < 20; i++){
    int idx = base + i;
    if (idx < N_NODES){
      row_start[idx] = run;
      float deg = (float)cnt[i] + 1.0f;
      dinv[idx] = rsqrtf(deg);
      cw[idx]   = 1.0f / deg;                    // self_norm; edge terms added by k_edge
      run += cnt[i];
    }
  }
}

// emeta.x = src * 128 (byte offset of src HALF-row in a half slab), emeta.y = f32 weight
__global__ void k_edge(const int* __restrict__ ei, const uint32_t* __restrict__ row_start,
                       uint32_t* __restrict__ cursor, const float* __restrict__ dinv,
                       float* __restrict__ cw, int2* __restrict__ emeta){
  int e = blockIdx.x * 256 + threadIdx.x;
  if (e >= N_EDGES) return;
  int s = ei[e];
  int d = ei[N_EDGES + e];
  float w = dinv[s] * dinv[d];
  atomicAdd(&cw[s], w);
  uint32_t off = atomicAdd(&cursor[d], 1u);
  uint32_t pos = row_start[d] + off;
  emeta[pos] = make_int2(s << 7, __float_as_int(w));
}

// W1 fp32 [k][f] -> f16 frag-packed: W1P[((k>>3)*128 + f)*8 + (k&7)]
__global__ void k_w1pack(const float* __restrict__ W1, uint16_t* __restrict__ W1P){
  int i = blockIdx.x * 256 + threadIdx.x;
  if (i >= 16 * 128 * 8) return;
  int e = i & 7, f = (i >> 3) & 127, q = i >> 10;
  int k = q * 8 + e;
  W1P[i] = (uint16_t)(pk_f16(W1[k * 128 + f], 0.0f) & 0xffffu);
}

// fp32 -> packed f16, half-split layout: xb[b][h][node][64 f16].
// lane j handles one 8-float group: (b, n, c) with c = feature-group 0..15, h = c>>3.
__global__ void k_cvt(const float4* __restrict__ x, uint4* __restrict__ xb, int n_grp){
  int i = blockIdx.x * 256 + threadIdx.x;
  int stride = gridDim.x * 256;
  for (; i < n_grp; i += stride){
    int b = i / (N_NODES * 16);
    int r = i - b * (N_NODES * 16);
    int n = r >> 4, c = r & 15;
    int h = c >> 3, co = c & 7;
    float4 f0 = x[2 * i];
    float4 f1 = x[2 * i + 1];
    uint4 o;
    o.x = pk_f16(f0.x, f0.y);
    o.y = pk_f16(f0.z, f0.w);
    o.z = pk_f16(f1.x, f1.y);
    o.w = pk_f16(f1.z, f1.w);
    xb[((size_t)(b * 2 + h) * N_NODES + n) * 8 + co] = o;
  }
}

// ---------------- phase A: y = (A_hat x), f16 in/out, fp32 accum, HALF-SPLIT ----------------
// grid (N/4, batches, 2 halves); z slowest -> one 2.56MB half-slab hot per XCD (fits 4MB L2).
// one wave per (dst node, batch, half). 8 lane-groups x 8 lanes: each group gathers a
// DIFFERENT edge's 128B half-row (8 edges per wave-load). 4-deep pipeline = 32 edges
// in flight. v_fma_mix consume (1 instr/feature). Same math as R9 -> same absmax.
__global__ __launch_bounds__(256) void k_agg(const uint32_t* __restrict__ xb, uint32_t* __restrict__ yb,
                      const int2* __restrict__ emeta, const uint32_t* __restrict__ row_start,
                      const uint32_t* __restrict__ hist, const float* __restrict__ dinv){
  const int wv = threadIdx.x >> 6, lane = threadIdx.x & 63;
  const int g = lane >> 3;                       // edge group 0..7
  const uint32_t s8 = (uint32_t)(lane & 7) * 16u; // 16B slot within 128B half-row
  int n = blockIdx.x * 4 + wv;
  const uint32_t bl = blockIdx.y, h = blockIdx.z;
  const char* xbase = (const char*)xb + (size_t)bl * ((size_t)N_NODES * 256)
                                      + (size_t)h * ((size_t)N_NODES * 128);

  float a0=0.f, a1=0.f, a2=0.f, a3=0.f, a4=0.f, a5=0.f, a6=0.f, a7=0.f;

#define CONS(VV, WW) do { \
    fmix_lo(a0, (VV).x, (WW)); fmix_hi(a1, (VV).x, (WW)); \
    fmix_lo(a2, (VV).y, (WW)); fmix_hi(a3, (VV).y, (WW)); \
    fmix_lo(a4, (VV).z, (WW)); fmix_hi(a5, (VV).z, (WW)); \
    fmix_lo(a6, (VV).w, (WW)); fmix_hi(a7, (VV).w, (WW)); \
  } while(0)

#define PREP(P, VV, WW) do { \
    uint32_t idx_ = sbase + (P)*8u + (uint32_t)g; \
    uint32_t ci_  = (idx_ < lim) ? idx_ : (lim - 1u); \
    uint32_t so_  = (uint32_t)__shfl(mx, (int)ci_); \
    float    wf_  = __int_as_float(__shfl(my, (int)ci_)); \
    WW = (idx_ < lim) ? wf_ : 0.0f; \
    VV = *reinterpret_cast<const uint4*>(xbase + (so_ + s8)); \
  } while(0)

  // self term: all 8 groups load the same half-row (HW broadcasts), weight self/8
  float di = dinv[n];
  {
    uint4 sv = *reinterpret_cast<const uint4*>(xbase + ((uint32_t)n * 128u + s8));
    float wself = di * di * 0.125f;
    CONS(sv, wself);
  }

  uint32_t rs  = (uint32_t)__builtin_amdgcn_readfirstlane((int)row_start[n]);
  uint32_t cnt = (uint32_t)__builtin_amdgcn_readfirstlane((int)hist[n]);

  for (uint32_t cbase = 0; cbase < cnt; cbase += 64u){
    uint32_t lim = cnt - cbase; if (lim > 64u) lim = 64u;   // edges in this chunk, >=1
    uint32_t cl = (uint32_t)lane; if (cl >= lim) cl = lim - 1u;
    int2 m = emeta[rs + cbase + cl];                        // one coalesced 512B load
    int mx = m.x, my = m.y;

    uint32_t sbase = 0;
    while (sbase + 32u <= lim){                             // full 32-edge super-steps
      uint4 p0, p1, p2, p3; float q0, q1, q2, q3;
      PREP(0, p0, q0); PREP(1, p1, q1); PREP(2, p2, q2); PREP(3, p3, q3);
      CONS(p0, q0); CONS(p1, q1); CONS(p2, q2); CONS(p3, q3);
      sbase += 32u;
    }
    if (sbase < lim){                                       // tail: 1..31 edges
      uint32_t live = lim - sbase;
      uint4 p0, p1, p2, p3; float q0, q1, q2, q3;
      PREP(0, p0, q0);
      if (live > 8u)  { PREP(1, p1, q1); }
      if (live > 16u) { PREP(2, p2, q2); }
      if (live > 24u) { PREP(3, p3, q3); }
      CONS(p0, q0);
      if (live > 8u)  { CONS(p1, q1); }
      if (live > 16u) { CONS(p2, q2); }
      if (live > 24u) { CONS(p3, q3); }
    }
  }
#undef PREP
#undef CONS

  // reduce over the 8 edge-groups: lanes {lane&7 equal} hold same features
  a0 += __shfl_xor(a0, 8); a0 += __shfl_xor(a0, 16); a0 += __shfl_xor(a0, 32);
  a1 += __shfl_xor(a1, 8); a1 += __shfl_xor(a1, 16); a1 += __shfl_xor(a1, 32);
  a2 += __shfl_xor(a2, 8); a2 += __shfl_xor(a2, 16); a2 += __shfl_xor(a2, 32);
  a3 += __shfl_xor(a3, 8); a3 += __shfl_xor(a3, 16); a3 += __shfl_xor(a3, 32);
  a4 += __shfl_xor(a4, 8); a4 += __shfl_xor(a4, 16); a4 += __shfl_xor(a4, 32);
  a5 += __shfl_xor(a5, 8); a5 += __shfl_xor(a5, 16); a5 += __shfl_xor(a5, 32);
  a6 += __shfl_xor(a6, 8); a6 += __shfl_xor(a6, 16); a6 += __shfl_xor(a6, 32);
  a7 += __shfl_xor(a7, 8); a7 += __shfl_xor(a7, 16); a7 += __shfl_xor(a7, 32);

  if (lane < 8){
    uint4 o;
    o.x = pk_f16(a0, a1);
    o.y = pk_f16(a2, a3);
    o.z = pk_f16(a4, a5);
    o.w = pk_f16(a6, a7);
    char* ybase = (char*)yb + (size_t)bl * ((size_t)N_NODES * 256)
                            + (size_t)h * ((size_t)N_NODES * 128);
    *reinterpret_cast<uint4*>(ybase + ((uint32_t)n * 128u + s8)) = o;
  }
}

// ---------------- phase B: S[b,f] += sum_n c[n]*relu(y[b,n,:]·W1[:,f] + b1[f]) ----------------
// 4 waves/block; each wave: W1 fully in registers (32 B-frags), loops 8 n-tiles of 16 rows.
// A-frags read from the half-split yb: k 0..63 in half0 row, 64..127 in half1 row.
__global__ __launch_bounds__(256) void k_gemm(const uint16_t* __restrict__ y,
                                              const uint16_t* __restrict__ W1P,
                                              const float* __restrict__ b1,
                                              const float* __restrict__ cw,
                                              float* __restrict__ S, int b_global0){
  const int w = threadIdx.x >> 6, lane = threadIdx.x & 63;
  const int l15 = lane & 15, q = lane >> 4;
  const int bl = blockIdx.y;

  // B-frags: lane l, elem e -> W1[k][ft*16 + l15], k = q32*32 + q*8 + e  (same k-map as A)
  v8h bfr[4][8];
  #pragma unroll
  for (int q32 = 0; q32 < 4; q32++)
    #pragma unroll
    for (int ft = 0; ft < 8; ft++)
      bfr[q32][ft] = *reinterpret_cast<const v8h*>(W1P + ((q32 * 4 + q) * 128 + ft * 16 + l15) * 8);

  float b1v[8];
  #pragma unroll
  for (int ft = 0; ft < 8; ft++) b1v[ft] = b1[ft * 16 + l15];

  float sacc[8] = {0.f,0.f,0.f,0.f,0.f,0.f,0.f,0.f};

  const int NT = N_NODES / 16;                   // 1250 full tiles
  int tile0 = (blockIdx.x * 4 + w) * 8;
  for (int t = 0; t < 8; t++){
    int tile = tile0 + t;
    if (tile >= NT) break;
    int n0 = tile * 16;
    const uint16_t* yr0 = y + ((size_t)(bl * 2 + 0) * N_NODES + n0 + l15) * 64 + q * 8;
    const uint16_t* yr1 = y + ((size_t)(bl * 2 + 1) * N_NODES + n0 + l15) * 64 + q * 8;
    v8h a0 = *reinterpret_cast<const v8h*>(yr0);        // k = 0..31 slice
    v8h a1 = *reinterpret_cast<const v8h*>(yr0 + 32);   // k = 32..63
    v8h a2 = *reinterpret_cast<const v8h*>(yr1);        // k = 64..95
    v8h a3 = *reinterpret_cast<const v8h*>(yr1 + 32);   // k = 96..127

    v4f acc[8];
    #pragma unroll
    for (int ft = 0; ft < 8; ft++) acc[ft] = (v4f){0.f,0.f,0.f,0.f};
    #pragma unroll
    for (int ft = 0; ft < 8; ft++) acc[ft] = __builtin_amdgcn_mfma_f32_16x16x32_f16(a0, bfr[0][ft], acc[ft], 0, 0, 0);
    #pragma unroll
    for (int ft = 0; ft < 8; ft++) acc[ft] = __builtin_amdgcn_mfma_f32_16x16x32_f16(a1, bfr[1][ft], acc[ft], 0, 0, 0);
    #pragma unroll
    for (int ft = 0; ft < 8; ft++) acc[ft] = __builtin_amdgcn_mfma_f32_16x16x32_f16(a2, bfr[2][ft], acc[ft], 0, 0, 0);
    #pragma unroll
    for (int ft = 0; ft < 8; ft++) acc[ft] = __builtin_amdgcn_mfma_f32_16x16x32_f16(a3, bfr[3][ft], acc[ft], 0, 0, 0);

    // epilogue: + b1, relu, * c[row], accumulate. D: row = n0 + q*4 + r, col = ft*16 + l15
    float4 cvv = *reinterpret_cast<const float4*>(cw + n0 + q * 4);
    float cvr[4] = {cvv.x, cvv.y, cvv.z, cvv.w};
    #pragma unroll
    for (int ft = 0; ft < 8; ft++){
      #pragma unroll
      for (int r = 0; r < 4; r++){
        float v = acc[ft][r] + b1v[ft];
        v = fmaxf(v, 0.0f);
        sacc[ft] = fmaf(v, cvr[r], sacc[ft]);
      }
    }
  }

  // reduce over q-groups (rows) -> col sums, then one atomic per (f)
  #pragma unroll
  for (int ft = 0; ft < 8; ft++){
    float v = sacc[ft];
    v += __shfl_xor(v, 16);
    v += __shfl_xor(v, 32);
    if (lane < 16) atomicAdd(&S[(b_global0 + bl) * DIM + ft * 16 + lane], v);
  }
}

// ---------------- final: out[b,f] = (S[b,:]/N)·W2[:,f] + b2[f] ----------------
__global__ void k_final(const float* __restrict__ S, const float* __restrict__ W2,
                        const float* __restrict__ b2, float* __restrict__ out){
  int i = blockIdx.x * 256 + threadIdx.x;
  if (i >= N_BATCH * DIM) return;
  int b = i >> 7, f = i & 127;
  float o = 0.0f;
  const float invN = 1.0f / (float)N_NODES;
  #pragma unroll 4
  for (int k = 0; k < 128; k++)
    o = fmaf(S[b * 128 + k], W2[k * 128 + f], o);
  out[i] = fmaf(o, invN, b2[f]);
}

// ---------------- host ----------------

extern "C" void kernel_launch(void* const* d_in, const int* in_sizes, int n_in,
                              void* d_out, int out_size, void* d_ws, size_t ws_size,
                              hipStream_t stream){
  const float* gene = (const float*)d_in[0];
  const int*   ei   = (const int*)d_in[1];
  const float* W1   = (const float*)d_in[2];
  const float* b1   = (const float*)d_in[3];
  const float* W2   = (const float*)d_in[4];
  const float* b2   = (const float*)d_in[5];
  float* out = (float*)d_out;

  char* base = (char*)d_ws;
  size_t off = 0;
  auto take = [&](size_t bytes)->char*{
    char* p = base + off;
    off = (off + bytes + 255) & ~(size_t)255;
    return p;
  };

  // zero zone: hist (N+1) | cursor (N) | S (B*128 f32)  -- one contiguous zero pass
  const int ZWORDS = (N_NODES + 1) + N_NODES + N_BATCH * DIM;
  uint32_t* zzone  = (uint32_t*)take((size_t)ZWORDS * 4);
  uint32_t* hist   = zzone;
  uint32_t* cursor = zzone + (N_NODES + 1);
  float*    S      = (float*)(zzone + (N_NODES + 1) + N_NODES);

  uint32_t* row_start = (uint32_t*)take((size_t)N_NODES * 4);
  float*    dinv      = (float*)take((size_t)N_NODES * 4);
  float*    cw        = (float*)take((size_t)N_NODES * 4);
  int2*     emeta     = (int2*)take((size_t)N_EDGES * 8);
  uint16_t* W1P       = (uint16_t*)take((size_t)16 * 128 * 8 * 2);

  // batch-chunked x/y f16 buffers sized to fit ws (half-split layout inside each slab)
  const size_t per_batch = (size_t)N_NODES * DIM * 2;   // 5.12 MB
  size_t remain = (ws_size > off) ? (ws_size - off) : 0;
  int C = (int)(remain / (2 * per_batch));
  if (C < 1) C = 1;
  if (C > N_BATCH) C = N_BATCH;
  uint32_t* xb = (uint32_t*)take(per_batch * C);
  uint32_t* yb = (uint32_t*)take(per_batch * C);

  k_zero<<<cdiv(ZWORDS, 256), 256, 0, stream>>>(zzone, ZWORDS);
  k_hist<<<cdiv(N_EDGES, 256), 256, 0, stream>>>(ei, hist);
  k_scan<<<1, 1024, 0, stream>>>(hist, row_start, dinv, cw);
  k_edge<<<cdiv(N_EDGES, 256), 256, 0, stream>>>(ei, row_start, cursor, dinv, cw, emeta);
  k_w1pack<<<64, 256, 0, stream>>>(W1, W1P);

  for (int b0 = 0; b0 < N_BATCH; b0 += C){
    int Cb = (N_BATCH - b0 < C) ? (N_BATCH - b0) : C;
    int ngrp = Cb * N_NODES * 16;                 // 8-float groups
    int cvtb = cdiv(ngrp, 256 * 8); if (cvtb > 2048) cvtb = 2048;
    k_cvt<<<cvtb, 256, 0, stream>>>(((const float4*)gene) + (size_t)b0 * N_NODES * (DIM / 4),
                                    (uint4*)xb, ngrp);
    k_agg<<<dim3(N_NODES / 4, Cb, 2), 256, 0, stream>>>(xb, yb, emeta, row_start, hist, dinv);
    k_gemm<<<dim3(cdiv(N_NODES / 16, 32), Cb), 256, 0, stream>>>((const uint16_t*)yb, W1P, b1, cw, S, b0);
  }

  k_final<<<cdiv(N_BATCH * DIM, 256), 256, 0, stream>>>(S, W2, b2, out);
}

// Round 12
// 562.403 us; speedup vs baseline: 1.1998x; 1.1998x over previous
//
#include <hip/hip_runtime.h>
#include <stdint.h>

#define N_NODES 20000
#define N_EDGES 320000
#define N_BATCH 32
#define DIM     128

typedef _Float16 v8h __attribute__((ext_vector_type(8)));
typedef float v4f __attribute__((ext_vector_type(4)));

static inline int cdiv(int a, int b){ return (a + b - 1) / b; }

// pack two f32 -> two f16 (RTZ), single v_cvt_pkrtz_f16_f32 (GCN-era instr)
__device__ __forceinline__ uint32_t pk_f16(float lo, float hi){
  auto h = __builtin_amdgcn_cvt_pkrtz(lo, hi);   // __fp16 ext_vector(2)
  return __builtin_bit_cast(uint32_t, h);
}
// acc += f32(f16 from lo/hi half of u) * w  -- single v_fma_mix_f32 (gfx906+)
// VGPR-weight variants (self term):
__device__ __forceinline__ void fmix_lo(float& acc, uint32_t u, float w){
  asm("v_fma_mix_f32 %0, %1, %2, %0 op_sel:[0,0,0] op_sel_hi:[1,0,0]"
      : "+v"(acc) : "v"(u), "v"(w));
}
__device__ __forceinline__ void fmix_hi(float& acc, uint32_t u, float w){
  asm("v_fma_mix_f32 %0, %1, %2, %0 op_sel:[1,0,0] op_sel_hi:[1,0,0]"
      : "+v"(acc) : "v"(u), "v"(w));
}
// SGPR-weight variants (edge loop: weight is wave-uniform; 1 SGPR/instr allowed)
__device__ __forceinline__ void fmix_lo_s(float& acc, uint32_t u, float w){
  asm("v_fma_mix_f32 %0, %1, %2, %0 op_sel:[0,0,0] op_sel_hi:[1,0,0]"
      : "+v"(acc) : "v"(u), "s"(w));
}
__device__ __forceinline__ void fmix_hi_s(float& acc, uint32_t u, float w){
  asm("v_fma_mix_f32 %0, %1, %2, %0 op_sel:[1,0,0] op_sel_hi:[1,0,0]"
      : "+v"(acc) : "v"(u), "s"(w));
}

// ---------------- setup kernels ----------------

__global__ void k_zero(uint32_t* p, int n){
  int i = blockIdx.x * 256 + threadIdx.x;
  if (i < n) p[i] = 0u;
}

__global__ void k_hist(const int* __restrict__ ei, uint32_t* __restrict__ hist){
  int e = blockIdx.x * 256 + threadIdx.x;
  if (e < N_EDGES){
    int d = ei[N_EDGES + e];
    atomicAdd(&hist[d], 1u);
  }
}

// single-block exclusive scan of hist -> row_start; also deg-derived dinv, c-init
__global__ void k_scan(const uint32_t* __restrict__ hist, uint32_t* __restrict__ row_start,
                       float* __restrict__ dinv, float* __restrict__ cw){
  __shared__ uint32_t part[1024];
  const int t = threadIdx.x;
  const int base = t * 20;                       // 1024*20 = 20480 >= 20000
  uint32_t cnt[20];
  uint32_t s = 0;
  #pragma unroll
  for (int i = 0; i < 20; i++){
    int idx = base + i;
    uint32_t v = (idx < N_NODES) ? hist[idx] : 0u;
    cnt[i] = v; s += v;
  }
  part[t] = s;
  __syncthreads();
  for (int off = 1; off < 1024; off <<= 1){      // inclusive Hillis-Steele
    uint32_t v = part[t];
    uint32_t add = (t >= off) ? part[t - off] : 0u;
    __syncthreads();
    part[t] = v + add;
    __syncthreads();
  }
  uint32_t run = (t > 0) ? part[t - 1] : 0u;     // exclusive prefix
  #pragma unroll
  for (int i = 0; i < 20; i++){
    int idx = base + i;
    if (idx < N_NODES){
      row_start[idx] = run;
      float deg = (float)cnt[i] + 1.0f;
      dinv[idx] = rsqrtf(deg);
      cw[idx]   = 1.0f / deg;                    // self_norm; edge terms added by k_edge
      run += cnt[i];
    }
  }
}

// emeta.x = src * 256 (byte offset of src row in a batch slab), emeta.y = f32 weight bits
__global__ void k_edge(const int* __restrict__ ei, const uint32_t* __restrict__ row_start,
                       uint32_t* __restrict__ cursor, const float* __restrict__ dinv,
                       float* __restrict__ cw, int2* __restrict__ emeta){
  int e = blockIdx.x * 256 + threadIdx.x;
  if (e >= N_EDGES) return;
  int s = ei[e];
  int d = ei[N_EDGES + e];
  float w = dinv[s] * dinv[d];
  atomicAdd(&cw[s], w);
  uint32_t off = atomicAdd(&cursor[d], 1u);
  uint32_t pos = row_start[d] + off;
  emeta[pos] = make_int2(s << 8, __float_as_int(w));
}

// W1 fp32 [k][f] -> f16 frag-packed: W1P[((k>>3)*128 + f)*8 + (k&7)]
__global__ void k_w1pack(const float* __restrict__ W1, uint16_t* __restrict__ W1P){
  int i = blockIdx.x * 256 + threadIdx.x;
  if (i >= 16 * 128 * 8) return;
  int e = i & 7, f = (i >> 3) & 127, q = i >> 10;
  int k = q * 8 + e;
  W1P[i] = (uint16_t)(pk_f16(W1[k * 128 + f], 0.0f) & 0xffffu);
}

// fp32 -> packed f16: 32B read / 16B write per lane, cvt_pkrtz pack, grid-stride
__global__ void k_cvt(const float4* __restrict__ x, uint4* __restrict__ xb, int n_u4){
  int i = blockIdx.x * 256 + threadIdx.x;
  int stride = gridDim.x * 256;
  for (; i < n_u4; i += stride){
    float4 f0 = x[2 * i];
    float4 f1 = x[2 * i + 1];
    uint4 o;
    o.x = pk_f16(f0.x, f0.y);
    o.y = pk_f16(f0.z, f0.w);
    o.z = pk_f16(f1.x, f1.y);
    o.w = pk_f16(f1.z, f1.w);
    xb[i] = o;
  }
}

// ---------------- phase A: y = (A_hat x), f16 in/out, fp32 accum ----------------
// one wave per (dst node, batch). SCALAR-PIPE meta: rs/cnt/edge-(src,w) are wave-
// uniform -> readfirstlane-laundered indices make the compiler emit s_load for meta
// and saddr-form global_load_dword for gathers (voffset = lane*4, loop-invariant).
// All 64 lanes consume the SAME edge (256B row, dword/lane); each lane owns 2
// output features -> no cross-lane reduce. Per-edge VALU = 2 fmix (weight in SGPR).
// Unroll 8 -> 8 gathers (2KB) in flight per wave.
__global__ __launch_bounds__(256) void k_agg(const uint32_t* __restrict__ xb, uint32_t* __restrict__ yb,
                      const int2* __restrict__ emeta, const uint32_t* __restrict__ row_start,
                      const uint32_t* __restrict__ hist, const float* __restrict__ dinv){
  const int wv = threadIdx.x >> 6, lane = threadIdx.x & 63;
  const int n = blockIdx.x * 4 + wv;              // 20000 % 4 == 0 -> always valid
  const uint32_t bl = blockIdx.y;
  const char* xbase = (const char*)xb + (size_t)bl * ((size_t)N_NODES * 256);
  const uint32_t l4 = (uint32_t)lane * 4u;

  float a0 = 0.f, a1 = 0.f;

  // self term
  float di = dinv[n];
  {
    uint32_t sv = *reinterpret_cast<const uint32_t*>(xbase + ((uint32_t)n * 256u + l4));
    float ws = di * di;
    fmix_lo(a0, sv, ws); fmix_hi(a1, sv, ws);
  }

  uint32_t rs  = (uint32_t)__builtin_amdgcn_readfirstlane((int)row_start[n]);
  uint32_t cnt = (uint32_t)__builtin_amdgcn_readfirstlane((int)hist[n]);

  uint32_t i = 0;
  for (; i + 8u <= cnt; i += 8u){
    int so[8]; float wf[8];
    #pragma unroll
    for (int j = 0; j < 8; j++){
      int2 m = emeta[rs + i + (uint32_t)j];       // uniform index -> s_load
      so[j] = __builtin_amdgcn_readfirstlane(m.x);
      wf[j] = __int_as_float(__builtin_amdgcn_readfirstlane(m.y));
    }
    uint32_t v[8];
    #pragma unroll
    for (int j = 0; j < 8; j++)
      v[j] = *reinterpret_cast<const uint32_t*>(xbase + ((uint32_t)so[j] + l4));
    #pragma unroll
    for (int j = 0; j < 8; j++){
      fmix_lo_s(a0, v[j], wf[j]);
      fmix_hi_s(a1, v[j], wf[j]);
    }
  }
  for (; i < cnt; i++){                           // tail 0..7 edges
    int2 m = emeta[rs + i];
    int so_ = __builtin_amdgcn_readfirstlane(m.x);
    float wf_ = __int_as_float(__builtin_amdgcn_readfirstlane(m.y));
    uint32_t v_ = *reinterpret_cast<const uint32_t*>(xbase + ((uint32_t)so_ + l4));
    fmix_lo_s(a0, v_, wf_);
    fmix_hi_s(a1, v_, wf_);
  }

  char* ybase = (char*)yb + (size_t)bl * ((size_t)N_NODES * 256);
  *reinterpret_cast<uint32_t*>(ybase + ((uint32_t)n * 256u + l4)) = pk_f16(a0, a1);
}

// ---------------- phase B: S[b,f] += sum_n c[n]*relu(y[b,n,:]·W1[:,f] + b1[f]) ----------------
// 4 waves/block; each wave: W1 fully in registers (32 B-frags), loops 8 n-tiles of 16 rows
__global__ __launch_bounds__(256) void k_gemm(const uint16_t* __restrict__ y,
                                              const uint16_t* __restrict__ W1P,
                                              const float* __restrict__ b1,
                                              const float* __restrict__ cw,
                                              float* __restrict__ S, int b_global0){
  const int w = threadIdx.x >> 6, lane = threadIdx.x & 63;
  const int l15 = lane & 15, q = lane >> 4;
  const int bl = blockIdx.y;

  // B-frags: lane l, elem e -> W1[k][ft*16 + l15], k = q32*32 + q*8 + e  (same k-map as A)
  v8h bfr[4][8];
  #pragma unroll
  for (int q32 = 0; q32 < 4; q32++)
    #pragma unroll
    for (int ft = 0; ft < 8; ft++)
      bfr[q32][ft] = *reinterpret_cast<const v8h*>(W1P + ((q32 * 4 + q) * 128 + ft * 16 + l15) * 8);

  float b1v[8];
  #pragma unroll
  for (int ft = 0; ft < 8; ft++) b1v[ft] = b1[ft * 16 + l15];

  float sacc[8] = {0.f,0.f,0.f,0.f,0.f,0.f,0.f,0.f};

  const int NT = N_NODES / 16;                   // 1250 full tiles
  int tile0 = (blockIdx.x * 4 + w) * 8;
  for (int t = 0; t < 8; t++){
    int tile = tile0 + t;
    if (tile >= NT) break;
    int n0 = tile * 16;
    const uint16_t* yrow = y + ((size_t)bl * N_NODES + n0 + l15) * DIM + q * 8;
    v8h a0 = *reinterpret_cast<const v8h*>(yrow);
    v8h a1 = *reinterpret_cast<const v8h*>(yrow + 32);
    v8h a2 = *reinterpret_cast<const v8h*>(yrow + 64);
    v8h a3 = *reinterpret_cast<const v8h*>(yrow + 96);

    v4f acc[8];
    #pragma unroll
    for (int ft = 0; ft < 8; ft++) acc[ft] = (v4f){0.f,0.f,0.f,0.f};
    #pragma unroll
    for (int ft = 0; ft < 8; ft++) acc[ft] = __builtin_amdgcn_mfma_f32_16x16x32_f16(a0, bfr[0][ft], acc[ft], 0, 0, 0);
    #pragma unroll
    for (int ft = 0; ft < 8; ft++) acc[ft] = __builtin_amdgcn_mfma_f32_16x16x32_f16(a1, bfr[1][ft], acc[ft], 0, 0, 0);
    #pragma unroll
    for (int ft = 0; ft < 8; ft++) acc[ft] = __builtin_amdgcn_mfma_f32_16x16x32_f16(a2, bfr[2][ft], acc[ft], 0, 0, 0);
    #pragma unroll
    for (int ft = 0; ft < 8; ft++) acc[ft] = __builtin_amdgcn_mfma_f32_16x16x32_f16(a3, bfr[3][ft], acc[ft], 0, 0, 0);

    // epilogue: + b1, relu, * c[row], accumulate. D: row = n0 + q*4 + r, col = ft*16 + l15
    float4 cvv = *reinterpret_cast<const float4*>(cw + n0 + q * 4);
    float cvr[4] = {cvv.x, cvv.y, cvv.z, cvv.w};
    #pragma unroll
    for (int ft = 0; ft < 8; ft++){
      #pragma unroll
      for (int r = 0; r < 4; r++){
        float v = acc[ft][r] + b1v[ft];
        v = fmaxf(v, 0.0f);
        sacc[ft] = fmaf(v, cvr[r], sacc[ft]);
      }
    }
  }

  // reduce over q-groups (rows) -> col sums, then one atomic per (f)
  #pragma unroll
  for (int ft = 0; ft < 8; ft++){
    float v = sacc[ft];
    v += __shfl_xor(v, 16);
    v += __shfl_xor(v, 32);
    if (lane < 16) atomicAdd(&S[(b_global0 + bl) * DIM + ft * 16 + lane], v);
  }
}

// ---------------- final: out[b,f] = (S[b,:]/N)·W2[:,f] + b2[f] ----------------
__global__ void k_final(const float* __restrict__ S, const float* __restrict__ W2,
                        const float* __restrict__ b2, float* __restrict__ out){
  int i = blockIdx.x * 256 + threadIdx.x;
  if (i >= N_BATCH * DIM) return;
  int b = i >> 7, f = i & 127;
  float o = 0.0f;
  const float invN = 1.0f / (float)N_NODES;
  #pragma unroll 4
  for (int k = 0; k < 128; k++)
    o = fmaf(S[b * 128 + k], W2[k * 128 + f], o);
  out[i] = fmaf(o, invN, b2[f]);
}

// ---------------- host ----------------

extern "C" void kernel_launch(void* const* d_in, const int* in_sizes, int n_in,
                              void* d_out, int out_size, void* d_ws, size_t ws_size,
                              hipStream_t stream){
  const float* gene = (const float*)d_in[0];
  const int*   ei   = (const int*)d_in[1];
  const float* W1   = (const float*)d_in[2];
  const float* b1   = (const float*)d_in[3];
  const float* W2   = (const float*)d_in[4];
  const float* b2   = (const float*)d_in[5];
  float* out = (float*)d_out;

  char* base = (char*)d_ws;
  size_t off = 0;
  auto take = [&](size_t bytes)->char*{
    char* p = base + off;
    off = (off + bytes + 255) & ~(size_t)255;
    return p;
  };

  // zero zone: hist (N+1) | cursor (N) | S (B*128 f32)  -- one contiguous zero pass
  const int ZWORDS = (N_NODES + 1) + N_NODES + N_BATCH * DIM;
  uint32_t* zzone  = (uint32_t*)take((size_t)ZWORDS * 4);
  uint32_t* hist   = zzone;
  uint32_t* cursor = zzone + (N_NODES + 1);
  float*    S      = (float*)(zzone + (N_NODES + 1) + N_NODES);

  uint32_t* row_start = (uint32_t*)take((size_t)N_NODES * 4);
  float*    dinv      = (float*)take((size_t)N_NODES * 4);
  float*    cw        = (float*)take((size_t)N_NODES * 4);
  int2*     emeta     = (int2*)take((size_t)N_EDGES * 8);
  uint16_t* W1P       = (uint16_t*)take((size_t)16 * 128 * 8 * 2);

  // batch-chunked x/y f16 buffers sized to fit ws
  const size_t per_batch = (size_t)N_NODES * DIM * 2;   // 5.12 MB
  size_t remain = (ws_size > off) ? (ws_size - off) : 0;
  int C = (int)(remain / (2 * per_batch));
  if (C < 1) C = 1;
  if (C > N_BATCH) C = N_BATCH;
  uint32_t* xb = (uint32_t*)take(per_batch * C);
  uint32_t* yb = (uint32_t*)take(per_batch * C);

  k_zero<<<cdiv(ZWORDS, 256), 256, 0, stream>>>(zzone, ZWORDS);
  k_hist<<<cdiv(N_EDGES, 256), 256, 0, stream>>>(ei, hist);
  k_scan<<<1, 1024, 0, stream>>>(hist, row_start, dinv, cw);
  k_edge<<<cdiv(N_EDGES, 256), 256, 0, stream>>>(ei, row_start, cursor, dinv, cw, emeta);
  k_w1pack<<<64, 256, 0, stream>>>(W1, W1P);

  for (int b0 = 0; b0 < N_BATCH; b0 += C){
    int Cb = (N_BATCH - b0 < C) ? (N_BATCH - b0) : C;
    int nu4 = Cb * N_NODES * (DIM / 8);
    int cvtb = cdiv(nu4, 256 * 8); if (cvtb > 2048) cvtb = 2048;
    k_cvt<<<cvtb, 256, 0, stream>>>(((const float4*)gene) + (size_t)b0 * N_NODES * (DIM / 4),
                                    (uint4*)xb, nu4);
    k_agg<<<dim3(N_NODES / 4, Cb), 256, 0, stream>>>(xb, yb, emeta, row_start, hist, dinv);
    k_gemm<<<dim3(cdiv(N_NODES / 16, 32), Cb), 256, 0, stream>>>((const uint16_t*)yb, W1P, b1, cw, S, b0);
  }

  k_final<<<cdiv(N_BATCH * DIM, 256), 256, 0, stream>>>(S, W2, b2, out);
}

// Round 13
// 535.965 us; speedup vs baseline: 1.2590x; 1.0493x over previous
//
#include <hip/hip_runtime.h>
#include <stdint.h>

#define N_NODES 20000
#define N_EDGES 320000
#define N_BATCH 32
#define DIM     128

typedef _Float16 v8h __attribute__((ext_vector_type(8)));
typedef float v4f __attribute__((ext_vector_type(4)));

static inline int cdiv(int a, int b){ return (a + b - 1) / b; }

// pack two f32 -> two f16 (RTZ), single v_cvt_pkrtz_f16_f32 (GCN-era instr)
__device__ __forceinline__ uint32_t pk_f16(float lo, float hi){
  auto h = __builtin_amdgcn_cvt_pkrtz(lo, hi);   // __fp16 ext_vector(2)
  return __builtin_bit_cast(uint32_t, h);
}
// acc += f32(f16 from lo/hi half of u) * w  -- single v_fma_mix_f32 (gfx906+)
__device__ __forceinline__ void fmix_lo(float& acc, uint32_t u, float w){
  asm("v_fma_mix_f32 %0, %1, %2, %0 op_sel:[0,0,0] op_sel_hi:[1,0,0]"
      : "+v"(acc) : "v"(u), "v"(w));
}
__device__ __forceinline__ void fmix_hi(float& acc, uint32_t u, float w){
  asm("v_fma_mix_f32 %0, %1, %2, %0 op_sel:[1,0,0] op_sel_hi:[1,0,0]"
      : "+v"(acc) : "v"(u), "v"(w));
}

// ---------------- setup kernels ----------------

__global__ void k_zero(uint32_t* p, int n){
  int i = blockIdx.x * 256 + threadIdx.x;
  if (i < n) p[i] = 0u;
}

__global__ void k_hist(const int* __restrict__ ei, uint32_t* __restrict__ hist){
  int e = blockIdx.x * 256 + threadIdx.x;
  if (e < N_EDGES){
    int d = ei[N_EDGES + e];
    atomicAdd(&hist[d], 1u);
  }
}

// single-block exclusive scan of hist -> row_start; also deg-derived dinv, c-init
__global__ void k_scan(const uint32_t* __restrict__ hist, uint32_t* __restrict__ row_start,
                       float* __restrict__ dinv, float* __restrict__ cw){
  __shared__ uint32_t part[1024];
  const int t = threadIdx.x;
  const int base = t * 20;                       // 1024*20 = 20480 >= 20000
  uint32_t cnt[20];
  uint32_t s = 0;
  #pragma unroll
  for (int i = 0; i < 20; i++){
    int idx = base + i;
    uint32_t v = (idx < N_NODES) ? hist[idx] : 0u;
    cnt[i] = v; s += v;
  }
  part[t] = s;
  __syncthreads();
  for (int off = 1; off < 1024; off <<= 1){      // inclusive Hillis-Steele
    uint32_t v = part[t];
    uint32_t add = (t >= off) ? part[t - off] : 0u;
    __syncthreads();
    part[t] = v + add;
    __syncthreads();
  }
  uint32_t run = (t > 0) ? part[t - 1] : 0u;     // exclusive prefix
  #pragma unroll
  for (int i = 0; i < 20; i++){
    int idx = base + i;
    if (idx < N_NODES){
      row_start[idx] = run;
      float deg = (float)cnt[i] + 1.0f;
      dinv[idx] = rsqrtf(deg);
      cw[idx]   = 1.0f / deg;                    // self_norm; edge terms added by k_edge
      run += cnt[i];
    }
  }
}

// emeta.x = src * 256 (byte offset of src row in a batch slab), emeta.y = f32 weight bits
__global__ void k_edge(const int* __restrict__ ei, const uint32_t* __restrict__ row_start,
                       uint32_t* __restrict__ cursor, const float* __restrict__ dinv,
                       float* __restrict__ cw, int2* __restrict__ emeta){
  int e = blockIdx.x * 256 + threadIdx.x;
  if (e >= N_EDGES) return;
  int s = ei[e];
  int d = ei[N_EDGES + e];
  float w = dinv[s] * dinv[d];
  atomicAdd(&cw[s], w);
  uint32_t off = atomicAdd(&cursor[d], 1u);
  uint32_t pos = row_start[d] + off;
  emeta[pos] = make_int2(s << 8, __float_as_int(w));
}

// W1 fp32 [k][f] -> f16 frag-packed: W1P[((k>>3)*128 + f)*8 + (k&7)]
__global__ void k_w1pack(const float* __restrict__ W1, uint16_t* __restrict__ W1P){
  int i = blockIdx.x * 256 + threadIdx.x;
  if (i >= 16 * 128 * 8) return;
  int e = i & 7, f = (i >> 3) & 127, q = i >> 10;
  int k = q * 8 + e;
  W1P[i] = (uint16_t)(pk_f16(W1[k * 128 + f], 0.0f) & 0xffffu);
}

// fp32 -> packed f16: 32B read / 16B write per lane, cvt_pkrtz pack, grid-stride
__global__ void k_cvt(const float4* __restrict__ x, uint4* __restrict__ xb, int n_u4){
  int i = blockIdx.x * 256 + threadIdx.x;
  int stride = gridDim.x * 256;
  for (; i < n_u4; i += stride){
    float4 f0 = x[2 * i];
    float4 f1 = x[2 * i + 1];
    uint4 o;
    o.x = pk_f16(f0.x, f0.y);
    o.y = pk_f16(f0.z, f0.w);
    o.z = pk_f16(f1.x, f1.y);
    o.w = pk_f16(f1.z, f1.w);
    xb[i] = o;
  }
}

// ---------------- phase A: y = (A_hat x), f16 in/out, fp32 accum ----------------
// one wave per (dst node, batch). dwordx4 gathers: 16 lanes cover one 256B feature
// row; the 4 lane-groups (g = lane>>4) each handle a DIFFERENT edge -> 4 edges per
// wave-load. Edge meta chunk-loaded (64 edges) then bpermute-broadcast. 4-deep
// static software pipeline (16 edges / 4KB in flight per wave). Consume path uses
// v_fma_mix_f32 (1 instr per feature: f16 operand unpack fused into f32 FMA).
// R13: unchanged from R9 champion (260us); the lever this round is host-side
// chunking (C<=8) so the gather slab stays L3-resident.
__global__ __launch_bounds__(256) void k_agg(const uint32_t* __restrict__ xb, uint32_t* __restrict__ yb,
                      const int2* __restrict__ emeta, const uint32_t* __restrict__ row_start,
                      const uint32_t* __restrict__ hist, const float* __restrict__ dinv){
  const int wv = threadIdx.x >> 6, lane = threadIdx.x & 63;
  const int g = lane >> 4, s = lane & 15;
  int n = blockIdx.x * 4 + wv;
  if (n >= N_NODES) return;
  const uint32_t bl = blockIdx.y;
  const char* xbase = (const char*)xb + (size_t)bl * ((size_t)N_NODES * 256);
  const uint32_t s16 = (uint32_t)s * 16u;

  float a0=0.f, a1=0.f, a2=0.f, a3=0.f, a4=0.f, a5=0.f, a6=0.f, a7=0.f;

#define CONS(VV, WW) do { \
    fmix_lo(a0, (VV).x, (WW)); fmix_hi(a1, (VV).x, (WW)); \
    fmix_lo(a2, (VV).y, (WW)); fmix_hi(a3, (VV).y, (WW)); \
    fmix_lo(a4, (VV).z, (WW)); fmix_hi(a5, (VV).z, (WW)); \
    fmix_lo(a6, (VV).w, (WW)); fmix_hi(a7, (VV).w, (WW)); \
  } while(0)

#define PREP(P, VV, WW) do { \
    uint32_t idx_ = sbase + (P)*4u + (uint32_t)g; \
    uint32_t ci_  = (idx_ < lim) ? idx_ : (lim - 1u); \
    uint32_t so_  = (uint32_t)__shfl(mx, (int)ci_); \
    float    wf_  = __int_as_float(__shfl(my, (int)ci_)); \
    WW = (idx_ < lim) ? wf_ : 0.0f; \
    VV = *reinterpret_cast<const uint4*>(xbase + (so_ + s16)); \
  } while(0)

  // self term: all 4 groups load the same row (HW broadcasts), weight self/4
  float di = dinv[n];
  {
    uint4 sv = *reinterpret_cast<const uint4*>(xbase + ((uint32_t)n * 256u + s16));
    float wself = di * di * 0.25f;
    CONS(sv, wself);
  }

  uint32_t rs  = (uint32_t)__builtin_amdgcn_readfirstlane((int)row_start[n]);
  uint32_t cnt = (uint32_t)__builtin_amdgcn_readfirstlane((int)hist[n]);

  for (uint32_t cbase = 0; cbase < cnt; cbase += 64u){
    uint32_t lim = cnt - cbase; if (lim > 64u) lim = 64u;   // edges in this chunk, >=1
    uint32_t cl = (uint32_t)lane; if (cl >= lim) cl = lim - 1u;
    int2 m = emeta[rs + cbase + cl];                        // one coalesced 512B load
    int mx = m.x, my = m.y;

    uint32_t sbase = 0;
    while (sbase + 16u <= lim){                             // full 16-edge super-steps
      uint4 p0, p1, p2, p3; float q0, q1, q2, q3;
      PREP(0, p0, q0); PREP(1, p1, q1); PREP(2, p2, q2); PREP(3, p3, q3);
      CONS(p0, q0); CONS(p1, q1); CONS(p2, q2); CONS(p3, q3);
      sbase += 16u;
    }
    if (sbase < lim){                                       // tail: 1..15 edges
      uint32_t live = lim - sbase;
      uint4 p0, p1, p2, p3; float q0, q1, q2, q3;
      PREP(0, p0, q0);
      if (live > 4u)  { PREP(1, p1, q1); }
      if (live > 8u)  { PREP(2, p2, q2); }
      if (live > 12u) { PREP(3, p3, q3); }
      CONS(p0, q0);
      if (live > 4u)  { CONS(p1, q1); }
      if (live > 8u)  { CONS(p2, q2); }
      if (live > 12u) { CONS(p3, q3); }
    }
  }
#undef PREP
#undef CONS

  // reduce over the 4 edge-groups: lanes {s, s+16, s+32, s+48} hold same features
  a0 += __shfl_xor(a0, 16); a0 += __shfl_xor(a0, 32);
  a1 += __shfl_xor(a1, 16); a1 += __shfl_xor(a1, 32);
  a2 += __shfl_xor(a2, 16); a2 += __shfl_xor(a2, 32);
  a3 += __shfl_xor(a3, 16); a3 += __shfl_xor(a3, 32);
  a4 += __shfl_xor(a4, 16); a4 += __shfl_xor(a4, 32);
  a5 += __shfl_xor(a5, 16); a5 += __shfl_xor(a5, 32);
  a6 += __shfl_xor(a6, 16); a6 += __shfl_xor(a6, 32);
  a7 += __shfl_xor(a7, 16); a7 += __shfl_xor(a7, 32);

  if (lane < 16){
    uint4 o;
    o.x = pk_f16(a0, a1);
    o.y = pk_f16(a2, a3);
    o.z = pk_f16(a4, a5);
    o.w = pk_f16(a6, a7);
    char* ybase = (char*)yb + (size_t)bl * ((size_t)N_NODES * 256);
    *reinterpret_cast<uint4*>(ybase + ((uint32_t)n * 256u + s16)) = o;
  }
}

// ---------------- phase B: S[b,f] += sum_n c[n]*relu(y[b,n,:]·W1[:,f] + b1[f]) ----------------
// 4 waves/block; each wave: W1 fully in registers (32 B-frags), loops 8 n-tiles of 16 rows
__global__ __launch_bounds__(256) void k_gemm(const uint16_t* __restrict__ y,
                                              const uint16_t* __restrict__ W1P,
                                              const float* __restrict__ b1,
                                              const float* __restrict__ cw,
                                              float* __restrict__ S, int b_global0){
  const int w = threadIdx.x >> 6, lane = threadIdx.x & 63;
  const int l15 = lane & 15, q = lane >> 4;
  const int bl = blockIdx.y;

  // B-frags: lane l, elem e -> W1[k][ft*16 + l15], k = q32*32 + q*8 + e  (same k-map as A)
  v8h bfr[4][8];
  #pragma unroll
  for (int q32 = 0; q32 < 4; q32++)
    #pragma unroll
    for (int ft = 0; ft < 8; ft++)
      bfr[q32][ft] = *reinterpret_cast<const v8h*>(W1P + ((q32 * 4 + q) * 128 + ft * 16 + l15) * 8);

  float b1v[8];
  #pragma unroll
  for (int ft = 0; ft < 8; ft++) b1v[ft] = b1[ft * 16 + l15];

  float sacc[8] = {0.f,0.f,0.f,0.f,0.f,0.f,0.f,0.f};

  const int NT = N_NODES / 16;                   // 1250 full tiles
  int tile0 = (blockIdx.x * 4 + w) * 8;
  for (int t = 0; t < 8; t++){
    int tile = tile0 + t;
    if (tile >= NT) break;
    int n0 = tile * 16;
    const uint16_t* yrow = y + ((size_t)bl * N_NODES + n0 + l15) * DIM + q * 8;
    v8h a0 = *reinterpret_cast<const v8h*>(yrow);
    v8h a1 = *reinterpret_cast<const v8h*>(yrow + 32);
    v8h a2 = *reinterpret_cast<const v8h*>(yrow + 64);
    v8h a3 = *reinterpret_cast<const v8h*>(yrow + 96);

    v4f acc[8];
    #pragma unroll
    for (int ft = 0; ft < 8; ft++) acc[ft] = (v4f){0.f,0.f,0.f,0.f};
    #pragma unroll
    for (int ft = 0; ft < 8; ft++) acc[ft] = __builtin_amdgcn_mfma_f32_16x16x32_f16(a0, bfr[0][ft], acc[ft], 0, 0, 0);
    #pragma unroll
    for (int ft = 0; ft < 8; ft++) acc[ft] = __builtin_amdgcn_mfma_f32_16x16x32_f16(a1, bfr[1][ft], acc[ft], 0, 0, 0);
    #pragma unroll
    for (int ft = 0; ft < 8; ft++) acc[ft] = __builtin_amdgcn_mfma_f32_16x16x32_f16(a2, bfr[2][ft], acc[ft], 0, 0, 0);
    #pragma unroll
    for (int ft = 0; ft < 8; ft++) acc[ft] = __builtin_amdgcn_mfma_f32_16x16x32_f16(a3, bfr[3][ft], acc[ft], 0, 0, 0);

    // epilogue: + b1, relu, * c[row], accumulate. D: row = n0 + q*4 + r, col = ft*16 + l15
    float4 cvv = *reinterpret_cast<const float4*>(cw + n0 + q * 4);
    float cvr[4] = {cvv.x, cvv.y, cvv.z, cvv.w};
    #pragma unroll
    for (int ft = 0; ft < 8; ft++){
      #pragma unroll
      for (int r = 0; r < 4; r++){
        float v = acc[ft][r] + b1v[ft];
        v = fmaxf(v, 0.0f);
        sacc[ft] = fmaf(v, cvr[r], sacc[ft]);
      }
    }
  }

  // reduce over q-groups (rows) -> col sums, then one atomic per (f)
  #pragma unroll
  for (int ft = 0; ft < 8; ft++){
    float v = sacc[ft];
    v += __shfl_xor(v, 16);
    v += __shfl_xor(v, 32);
    if (lane < 16) atomicAdd(&S[(b_global0 + bl) * DIM + ft * 16 + lane], v);
  }
}

// ---------------- final: out[b,f] = (S[b,:]/N)·W2[:,f] + b2[f] ----------------
__global__ void k_final(const float* __restrict__ S, const float* __restrict__ W2,
                        const float* __restrict__ b2, float* __restrict__ out){
  int i = blockIdx.x * 256 + threadIdx.x;
  if (i >= N_BATCH * DIM) return;
  int b = i >> 7, f = i & 127;
  float o = 0.0f;
  const float invN = 1.0f / (float)N_NODES;
  #pragma unroll 4
  for (int k = 0; k < 128; k++)
    o = fmaf(S[b * 128 + k], W2[k * 128 + f], o);
  out[i] = fmaf(o, invN, b2[f]);
}

// ---------------- host ----------------

extern "C" void kernel_launch(void* const* d_in, const int* in_sizes, int n_in,
                              void* d_out, int out_size, void* d_ws, size_t ws_size,
                              hipStream_t stream){
  const float* gene = (const float*)d_in[0];
  const int*   ei   = (const int*)d_in[1];
  const float* W1   = (const float*)d_in[2];
  const float* b1   = (const float*)d_in[3];
  const float* W2   = (const float*)d_in[4];
  const float* b2   = (const float*)d_in[5];
  float* out = (float*)d_out;

  char* base = (char*)d_ws;
  size_t off = 0;
  auto take = [&](size_t bytes)->char*{
    char* p = base + off;
    off = (off + bytes + 255) & ~(size_t)255;
    return p;
  };

  // zero zone: hist (N+1) | cursor (N) | S (B*128 f32)  -- one contiguous zero pass
  const int ZWORDS = (N_NODES + 1) + N_NODES + N_BATCH * DIM;
  uint32_t* zzone  = (uint32_t*)take((size_t)ZWORDS * 4);
  uint32_t* hist   = zzone;
  uint32_t* cursor = zzone + (N_NODES + 1);
  float*    S      = (float*)(zzone + (N_NODES + 1) + N_NODES);

  uint32_t* row_start = (uint32_t*)take((size_t)N_NODES * 4);
  float*    dinv      = (float*)take((size_t)N_NODES * 4);
  float*    cw        = (float*)take((size_t)N_NODES * 4);
  int2*     emeta     = (int2*)take((size_t)N_EDGES * 8);
  uint16_t* W1P       = (uint16_t*)take((size_t)16 * 128 * 8 * 2);

  // batch-chunked x/y f16 buffers. C capped at 8: per-chunk xb+yb = 82 MB stays
  // L3-resident (256 MB) during k_agg -> gathers never fall to HBM (was 778 MB
  // HBM re-fetch at C=32 because xb+yb = 328 MB thrashed L3).
  const size_t per_batch = (size_t)N_NODES * DIM * 2;   // 5.12 MB
  size_t remain = (ws_size > off) ? (ws_size - off) : 0;
  int C = (int)(remain / (2 * per_batch));
  if (C < 1) C = 1;
  if (C > 8) C = 8;
  uint32_t* xb = (uint32_t*)take(per_batch * C);
  uint32_t* yb = (uint32_t*)take(per_batch * C);

  k_zero<<<cdiv(ZWORDS, 256), 256, 0, stream>>>(zzone, ZWORDS);
  k_hist<<<cdiv(N_EDGES, 256), 256, 0, stream>>>(ei, hist);
  k_scan<<<1, 1024, 0, stream>>>(hist, row_start, dinv, cw);
  k_edge<<<cdiv(N_EDGES, 256), 256, 0, stream>>>(ei, row_start, cursor, dinv, cw, emeta);
  k_w1pack<<<64, 256, 0, stream>>>(W1, W1P);

  for (int b0 = 0; b0 < N_BATCH; b0 += C){
    int Cb = (N_BATCH - b0 < C) ? (N_BATCH - b0) : C;
    int nu4 = Cb * N_NODES * (DIM / 8);
    int cvtb = cdiv(nu4, 256 * 8); if (cvtb > 2048) cvtb = 2048;
    k_cvt<<<cvtb, 256, 0, stream>>>(((const float4*)gene) + (size_t)b0 * N_NODES * (DIM / 4),
                                    (uint4*)xb, nu4);
    k_agg<<<dim3(N_NODES / 4, Cb), 256, 0, stream>>>(xb, yb, emeta, row_start, hist, dinv);
    k_gemm<<<dim3(cdiv(N_NODES / 16, 32), Cb), 256, 0, stream>>>((const uint16_t*)yb, W1P, b1, cw, S, b0);
  }

  k_final<<<cdiv(N_BATCH * DIM, 256), 256, 0, stream>>>(S, W2, b2, out);
}

// Round 14
// 525.384 us; speedup vs baseline: 1.2844x; 1.0201x over previous
//
#include <hip/hip_runtime.h>
#include <stdint.h>

#define N_NODES 20000
#define N_EDGES 320000
#define N_BATCH 32
#define DIM     128

typedef _Float16 v8h __attribute__((ext_vector_type(8)));
typedef float v4f __attribute__((ext_vector_type(4)));

static inline int cdiv(int a, int b){ return (a + b - 1) / b; }

// pack two f32 -> two f16 (RTZ), single v_cvt_pkrtz_f16_f32 (GCN-era instr)
__device__ __forceinline__ uint32_t pk_f16(float lo, float hi){
  auto h = __builtin_amdgcn_cvt_pkrtz(lo, hi);   // __fp16 ext_vector(2)
  return __builtin_bit_cast(uint32_t, h);
}
// acc += f32(f16 from lo/hi half of u) * w  -- single v_fma_mix_f32 (gfx906+)
__device__ __forceinline__ void fmix_lo(float& acc, uint32_t u, float w){
  asm("v_fma_mix_f32 %0, %1, %2, %0 op_sel:[0,0,0] op_sel_hi:[1,0,0]"
      : "+v"(acc) : "v"(u), "v"(w));
}
__device__ __forceinline__ void fmix_hi(float& acc, uint32_t u, float w){
  asm("v_fma_mix_f32 %0, %1, %2, %0 op_sel:[1,0,0] op_sel_hi:[1,0,0]"
      : "+v"(acc) : "v"(u), "v"(w));
}

// ---------------- setup kernels ----------------

__global__ void k_zero(uint32_t* p, int n){
  int i = blockIdx.x * 256 + threadIdx.x;
  if (i < n) p[i] = 0u;
}

__global__ void k_hist(const int* __restrict__ ei, uint32_t* __restrict__ hist){
  int e = blockIdx.x * 256 + threadIdx.x;
  if (e < N_EDGES){
    int d = ei[N_EDGES + e];
    atomicAdd(&hist[d], 1u);
  }
}

// single-block exclusive scan of hist -> row_start; also deg-derived dinv, c-init
__global__ void k_scan(const uint32_t* __restrict__ hist, uint32_t* __restrict__ row_start,
                       float* __restrict__ dinv, float* __restrict__ cw){
  __shared__ uint32_t part[1024];
  const int t = threadIdx.x;
  const int base = t * 20;                       // 1024*20 = 20480 >= 20000
  uint32_t cnt[20];
  uint32_t s = 0;
  #pragma unroll
  for (int i = 0; i < 20; i++){
    int idx = base + i;
    uint32_t v = (idx < N_NODES) ? hist[idx] : 0u;
    cnt[i] = v; s += v;
  }
  part[t] = s;
  __syncthreads();
  for (int off = 1; off < 1024; off <<= 1){      // inclusive Hillis-Steele
    uint32_t v = part[t];
    uint32_t add = (t >= off) ? part[t - off] : 0u;
    __syncthreads();
    part[t] = v + add;
    __syncthreads();
  }
  uint32_t run = (t > 0) ? part[t - 1] : 0u;     // exclusive prefix
  #pragma unroll
  for (int i = 0; i < 20; i++){
    int idx = base + i;
    if (idx < N_NODES){
      row_start[idx] = run;
      float deg = (float)cnt[i] + 1.0f;
      dinv[idx] = rsqrtf(deg);
      cw[idx]   = 1.0f / deg;                    // self_norm; edge terms added by k_edge
      run += cnt[i];
    }
  }
}

// emeta.x = src * 256 (byte offset of src row in a batch slab), emeta.y = f32 weight bits
__global__ void k_edge(const int* __restrict__ ei, const uint32_t* __restrict__ row_start,
                       uint32_t* __restrict__ cursor, const float* __restrict__ dinv,
                       float* __restrict__ cw, int2* __restrict__ emeta){
  int e = blockIdx.x * 256 + threadIdx.x;
  if (e >= N_EDGES) return;
  int s = ei[e];
  int d = ei[N_EDGES + e];
  float w = dinv[s] * dinv[d];
  atomicAdd(&cw[s], w);
  uint32_t off = atomicAdd(&cursor[d], 1u);
  uint32_t pos = row_start[d] + off;
  emeta[pos] = make_int2(s << 8, __float_as_int(w));
}

// W1 fp32 [k][f] -> f16 frag-packed: W1P[((k>>3)*128 + f)*8 + (k&7)]
__global__ void k_w1pack(const float* __restrict__ W1, uint16_t* __restrict__ W1P){
  int i = blockIdx.x * 256 + threadIdx.x;
  if (i >= 16 * 128 * 8) return;
  int e = i & 7, f = (i >> 3) & 127, q = i >> 10;
  int k = q * 8 + e;
  W1P[i] = (uint16_t)(pk_f16(W1[k * 128 + f], 0.0f) & 0xffffu);
}

// fp32 -> packed f16: 32B read / 16B write per lane, cvt_pkrtz pack, grid-stride
__global__ void k_cvt(const float4* __restrict__ x, uint4* __restrict__ xb, int n_u4){
  int i = blockIdx.x * 256 + threadIdx.x;
  int stride = gridDim.x * 256;
  for (; i < n_u4; i += stride){
    float4 f0 = x[2 * i];
    float4 f1 = x[2 * i + 1];
    uint4 o;
    o.x = pk_f16(f0.x, f0.y);
    o.y = pk_f16(f0.z, f0.w);
    o.z = pk_f16(f1.x, f1.y);
    o.w = pk_f16(f1.z, f1.w);
    xb[i] = o;
  }
}

// ---------------- phase A: y = (A_hat x), f16 in/out, fp32 accum, 2 BATCHES/WAVE ----
// R9 champion structure (dwordx4 gathers, 4 edge-groups, 64-edge meta prefetch,
// 4-deep pipeline, v_fma_mix consume) with ONE change: each wave serves batches
// (2*by, 2*by+1), reusing every PREP (idx/clamp/shfl/select) for two slabs.
// Per-edge-work wave instructions drop ~26%; in-flight gathers double to 8KB/wave.
__global__ __launch_bounds__(256) void k_agg(const uint32_t* __restrict__ xb, uint32_t* __restrict__ yb,
                      const int2* __restrict__ emeta, const uint32_t* __restrict__ row_start,
                      const uint32_t* __restrict__ hist, const float* __restrict__ dinv, int Cb){
  const int wv = threadIdx.x >> 6, lane = threadIdx.x & 63;
  const int g = lane >> 4, s = lane & 15;
  int n = blockIdx.x * 4 + wv;
  if (n >= N_NODES) return;
  const int bl0 = (int)blockIdx.y * 2;
  const int bl1 = bl0 + 1;
  const bool two = (bl1 < Cb);
  const char* xbA = (const char*)xb + (size_t)bl0 * ((size_t)N_NODES * 256);
  const char* xbB = (const char*)xb + (size_t)(two ? bl1 : bl0) * ((size_t)N_NODES * 256);
  const uint32_t s16 = (uint32_t)s * 16u;

  float aA0=0.f, aA1=0.f, aA2=0.f, aA3=0.f, aA4=0.f, aA5=0.f, aA6=0.f, aA7=0.f;
  float aB0=0.f, aB1=0.f, aB2=0.f, aB3=0.f, aB4=0.f, aB5=0.f, aB6=0.f, aB7=0.f;

#define CONS2(VA, VB, WW) do { \
    fmix_lo(aA0, (VA).x, (WW)); fmix_hi(aA1, (VA).x, (WW)); \
    fmix_lo(aA2, (VA).y, (WW)); fmix_hi(aA3, (VA).y, (WW)); \
    fmix_lo(aA4, (VA).z, (WW)); fmix_hi(aA5, (VA).z, (WW)); \
    fmix_lo(aA6, (VA).w, (WW)); fmix_hi(aA7, (VA).w, (WW)); \
    fmix_lo(aB0, (VB).x, (WW)); fmix_hi(aB1, (VB).x, (WW)); \
    fmix_lo(aB2, (VB).y, (WW)); fmix_hi(aB3, (VB).y, (WW)); \
    fmix_lo(aB4, (VB).z, (WW)); fmix_hi(aB5, (VB).z, (WW)); \
    fmix_lo(aB6, (VB).w, (WW)); fmix_hi(aB7, (VB).w, (WW)); \
  } while(0)

#define PREP2(P, VA, VB, WW) do { \
    uint32_t idx_ = sbase + (P)*4u + (uint32_t)g; \
    uint32_t ci_  = (idx_ < lim) ? idx_ : (lim - 1u); \
    uint32_t so_  = (uint32_t)__shfl(mx, (int)ci_); \
    float    wf_  = __int_as_float(__shfl(my, (int)ci_)); \
    WW = (idx_ < lim) ? wf_ : 0.0f; \
    VA = *reinterpret_cast<const uint4*>(xbA + (so_ + s16)); \
    VB = *reinterpret_cast<const uint4*>(xbB + (so_ + s16)); \
  } while(0)

  // self term: all 4 groups load the same row (HW broadcasts), weight self/4
  float di = dinv[n];
  {
    uint4 svA = *reinterpret_cast<const uint4*>(xbA + ((uint32_t)n * 256u + s16));
    uint4 svB = *reinterpret_cast<const uint4*>(xbB + ((uint32_t)n * 256u + s16));
    float wself = di * di * 0.25f;
    CONS2(svA, svB, wself);
  }

  uint32_t rs  = (uint32_t)__builtin_amdgcn_readfirstlane((int)row_start[n]);
  uint32_t cnt = (uint32_t)__builtin_amdgcn_readfirstlane((int)hist[n]);

  for (uint32_t cbase = 0; cbase < cnt; cbase += 64u){
    uint32_t lim = cnt - cbase; if (lim > 64u) lim = 64u;   // edges in this chunk, >=1
    uint32_t cl = (uint32_t)lane; if (cl >= lim) cl = lim - 1u;
    int2 m = emeta[rs + cbase + cl];                        // one coalesced 512B load
    int mx = m.x, my = m.y;

    uint32_t sbase = 0;
    while (sbase + 16u <= lim){                             // full 16-edge super-steps
      uint4 pA0, pA1, pA2, pA3, pB0, pB1, pB2, pB3; float q0, q1, q2, q3;
      PREP2(0, pA0, pB0, q0); PREP2(1, pA1, pB1, q1);
      PREP2(2, pA2, pB2, q2); PREP2(3, pA3, pB3, q3);
      CONS2(pA0, pB0, q0); CONS2(pA1, pB1, q1);
      CONS2(pA2, pB2, q2); CONS2(pA3, pB3, q3);
      sbase += 16u;
    }
    if (sbase < lim){                                       // tail: 1..15 edges
      uint32_t live = lim - sbase;
      uint4 pA0, pA1, pA2, pA3, pB0, pB1, pB2, pB3; float q0, q1, q2, q3;
      PREP2(0, pA0, pB0, q0);
      if (live > 4u)  { PREP2(1, pA1, pB1, q1); }
      if (live > 8u)  { PREP2(2, pA2, pB2, q2); }
      if (live > 12u) { PREP2(3, pA3, pB3, q3); }
      CONS2(pA0, pB0, q0);
      if (live > 4u)  { CONS2(pA1, pB1, q1); }
      if (live > 8u)  { CONS2(pA2, pB2, q2); }
      if (live > 12u) { CONS2(pA3, pB3, q3); }
    }
  }
#undef PREP2
#undef CONS2

  // reduce over the 4 edge-groups: lanes {s, s+16, s+32, s+48} hold same features
  aA0 += __shfl_xor(aA0, 16); aA0 += __shfl_xor(aA0, 32);
  aA1 += __shfl_xor(aA1, 16); aA1 += __shfl_xor(aA1, 32);
  aA2 += __shfl_xor(aA2, 16); aA2 += __shfl_xor(aA2, 32);
  aA3 += __shfl_xor(aA3, 16); aA3 += __shfl_xor(aA3, 32);
  aA4 += __shfl_xor(aA4, 16); aA4 += __shfl_xor(aA4, 32);
  aA5 += __shfl_xor(aA5, 16); aA5 += __shfl_xor(aA5, 32);
  aA6 += __shfl_xor(aA6, 16); aA6 += __shfl_xor(aA6, 32);
  aA7 += __shfl_xor(aA7, 16); aA7 += __shfl_xor(aA7, 32);
  aB0 += __shfl_xor(aB0, 16); aB0 += __shfl_xor(aB0, 32);
  aB1 += __shfl_xor(aB1, 16); aB1 += __shfl_xor(aB1, 32);
  aB2 += __shfl_xor(aB2, 16); aB2 += __shfl_xor(aB2, 32);
  aB3 += __shfl_xor(aB3, 16); aB3 += __shfl_xor(aB3, 32);
  aB4 += __shfl_xor(aB4, 16); aB4 += __shfl_xor(aB4, 32);
  aB5 += __shfl_xor(aB5, 16); aB5 += __shfl_xor(aB5, 32);
  aB6 += __shfl_xor(aB6, 16); aB6 += __shfl_xor(aB6, 32);
  aB7 += __shfl_xor(aB7, 16); aB7 += __shfl_xor(aB7, 32);

  if (lane < 16){
    uint4 oA;
    oA.x = pk_f16(aA0, aA1);
    oA.y = pk_f16(aA2, aA3);
    oA.z = pk_f16(aA4, aA5);
    oA.w = pk_f16(aA6, aA7);
    char* ybA = (char*)yb + (size_t)bl0 * ((size_t)N_NODES * 256);
    *reinterpret_cast<uint4*>(ybA + ((uint32_t)n * 256u + s16)) = oA;
    if (two){
      uint4 oB;
      oB.x = pk_f16(aB0, aB1);
      oB.y = pk_f16(aB2, aB3);
      oB.z = pk_f16(aB4, aB5);
      oB.w = pk_f16(aB6, aB7);
      char* ybB = (char*)yb + (size_t)bl1 * ((size_t)N_NODES * 256);
      *reinterpret_cast<uint4*>(ybB + ((uint32_t)n * 256u + s16)) = oB;
    }
  }
}

// ---------------- phase B: S[b,f] += sum_n c[n]*relu(y[b,n,:]·W1[:,f] + b1[f]) ----------------
// 4 waves/block; each wave: W1 fully in registers (32 B-frags), loops 8 n-tiles of 16 rows
__global__ __launch_bounds__(256) void k_gemm(const uint16_t* __restrict__ y,
                                              const uint16_t* __restrict__ W1P,
                                              const float* __restrict__ b1,
                                              const float* __restrict__ cw,
                                              float* __restrict__ S, int b_global0){
  const int w = threadIdx.x >> 6, lane = threadIdx.x & 63;
  const int l15 = lane & 15, q = lane >> 4;
  const int bl = blockIdx.y;

  // B-frags: lane l, elem e -> W1[k][ft*16 + l15], k = q32*32 + q*8 + e  (same k-map as A)
  v8h bfr[4][8];
  #pragma unroll
  for (int q32 = 0; q32 < 4; q32++)
    #pragma unroll
    for (int ft = 0; ft < 8; ft++)
      bfr[q32][ft] = *reinterpret_cast<const v8h*>(W1P + ((q32 * 4 + q) * 128 + ft * 16 + l15) * 8);

  float b1v[8];
  #pragma unroll
  for (int ft = 0; ft < 8; ft++) b1v[ft] = b1[ft * 16 + l15];

  float sacc[8] = {0.f,0.f,0.f,0.f,0.f,0.f,0.f,0.f};

  const int NT = N_NODES / 16;                   // 1250 full tiles
  int tile0 = (blockIdx.x * 4 + w) * 8;
  for (int t = 0; t < 8; t++){
    int tile = tile0 + t;
    if (tile >= NT) break;
    int n0 = tile * 16;
    const uint16_t* yrow = y + ((size_t)bl * N_NODES + n0 + l15) * DIM + q * 8;
    v8h a0 = *reinterpret_cast<const v8h*>(yrow);
    v8h a1 = *reinterpret_cast<const v8h*>(yrow + 32);
    v8h a2 = *reinterpret_cast<const v8h*>(yrow + 64);
    v8h a3 = *reinterpret_cast<const v8h*>(yrow + 96);

    v4f acc[8];
    #pragma unroll
    for (int ft = 0; ft < 8; ft++) acc[ft] = (v4f){0.f,0.f,0.f,0.f};
    #pragma unroll
    for (int ft = 0; ft < 8; ft++) acc[ft] = __builtin_amdgcn_mfma_f32_16x16x32_f16(a0, bfr[0][ft], acc[ft], 0, 0, 0);
    #pragma unroll
    for (int ft = 0; ft < 8; ft++) acc[ft] = __builtin_amdgcn_mfma_f32_16x16x32_f16(a1, bfr[1][ft], acc[ft], 0, 0, 0);
    #pragma unroll
    for (int ft = 0; ft < 8; ft++) acc[ft] = __builtin_amdgcn_mfma_f32_16x16x32_f16(a2, bfr[2][ft], acc[ft], 0, 0, 0);
    #pragma unroll
    for (int ft = 0; ft < 8; ft++) acc[ft] = __builtin_amdgcn_mfma_f32_16x16x32_f16(a3, bfr[3][ft], acc[ft], 0, 0, 0);

    // epilogue: + b1, relu, * c[row], accumulate. D: row = n0 + q*4 + r, col = ft*16 + l15
    float4 cvv = *reinterpret_cast<const float4*>(cw + n0 + q * 4);
    float cvr[4] = {cvv.x, cvv.y, cvv.z, cvv.w};
    #pragma unroll
    for (int ft = 0; ft < 8; ft++){
      #pragma unroll
      for (int r = 0; r < 4; r++){
        float v = acc[ft][r] + b1v[ft];
        v = fmaxf(v, 0.0f);
        sacc[ft] = fmaf(v, cvr[r], sacc[ft]);
      }
    }
  }

  // reduce over q-groups (rows) -> col sums, then one atomic per (f)
  #pragma unroll
  for (int ft = 0; ft < 8; ft++){
    float v = sacc[ft];
    v += __shfl_xor(v, 16);
    v += __shfl_xor(v, 32);
    if (lane < 16) atomicAdd(&S[(b_global0 + bl) * DIM + ft * 16 + lane], v);
  }
}

// ---------------- final: out[b,f] = (S[b,:]/N)·W2[:,f] + b2[f] ----------------
__global__ void k_final(const float* __restrict__ S, const float* __restrict__ W2,
                        const float* __restrict__ b2, float* __restrict__ out){
  int i = blockIdx.x * 256 + threadIdx.x;
  if (i >= N_BATCH * DIM) return;
  int b = i >> 7, f = i & 127;
  float o = 0.0f;
  const float invN = 1.0f / (float)N_NODES;
  #pragma unroll 4
  for (int k = 0; k < 128; k++)
    o = fmaf(S[b * 128 + k], W2[k * 128 + f], o);
  out[i] = fmaf(o, invN, b2[f]);
}

// ---------------- host ----------------

extern "C" void kernel_launch(void* const* d_in, const int* in_sizes, int n_in,
                              void* d_out, int out_size, void* d_ws, size_t ws_size,
                              hipStream_t stream){
  const float* gene = (const float*)d_in[0];
  const int*   ei   = (const int*)d_in[1];
  const float* W1   = (const float*)d_in[2];
  const float* b1   = (const float*)d_in[3];
  const float* W2   = (const float*)d_in[4];
  const float* b2   = (const float*)d_in[5];
  float* out = (float*)d_out;

  char* base = (char*)d_ws;
  size_t off = 0;
  auto take = [&](size_t bytes)->char*{
    char* p = base + off;
    off = (off + bytes + 255) & ~(size_t)255;
    return p;
  };

  // zero zone: hist (N+1) | cursor (N) | S (B*128 f32)  -- one contiguous zero pass
  const int ZWORDS = (N_NODES + 1) + N_NODES + N_BATCH * DIM;
  uint32_t* zzone  = (uint32_t*)take((size_t)ZWORDS * 4);
  uint32_t* hist   = zzone;
  uint32_t* cursor = zzone + (N_NODES + 1);
  float*    S      = (float*)(zzone + (N_NODES + 1) + N_NODES);

  uint32_t* row_start = (uint32_t*)take((size_t)N_NODES * 4);
  float*    dinv      = (float*)take((size_t)N_NODES * 4);
  float*    cw        = (float*)take((size_t)N_NODES * 4);
  int2*     emeta     = (int2*)take((size_t)N_EDGES * 8);
  uint16_t* W1P       = (uint16_t*)take((size_t)16 * 128 * 8 * 2);

  // batch-chunked x/y f16 buffers sized to fit ws (R9 behavior: C up to 32)
  const size_t per_batch = (size_t)N_NODES * DIM * 2;   // 5.12 MB
  size_t remain = (ws_size > off) ? (ws_size - off) : 0;
  int C = (int)(remain / (2 * per_batch));
  if (C < 1) C = 1;
  if (C > N_BATCH) C = N_BATCH;
  uint32_t* xb = (uint32_t*)take(per_batch * C);
  uint32_t* yb = (uint32_t*)take(per_batch * C);

  k_zero<<<cdiv(ZWORDS, 256), 256, 0, stream>>>(zzone, ZWORDS);
  k_hist<<<cdiv(N_EDGES, 256), 256, 0, stream>>>(ei, hist);
  k_scan<<<1, 1024, 0, stream>>>(hist, row_start, dinv, cw);
  k_edge<<<cdiv(N_EDGES, 256), 256, 0, stream>>>(ei, row_start, cursor, dinv, cw, emeta);
  k_w1pack<<<64, 256, 0, stream>>>(W1, W1P);

  for (int b0 = 0; b0 < N_BATCH; b0 += C){
    int Cb = (N_BATCH - b0 < C) ? (N_BATCH - b0) : C;
    int nu4 = Cb * N_NODES * (DIM / 8);
    int cvtb = cdiv(nu4, 256 * 8); if (cvtb > 2048) cvtb = 2048;
    k_cvt<<<cvtb, 256, 0, stream>>>(((const float4*)gene) + (size_t)b0 * N_NODES * (DIM / 4),
                                    (uint4*)xb, nu4);
    k_agg<<<dim3(N_NODES / 4, (Cb + 1) / 2), 256, 0, stream>>>(xb, yb, emeta, row_start,
                                                               hist, dinv, Cb);
    k_gemm<<<dim3(cdiv(N_NODES / 16, 32), Cb), 256, 0, stream>>>((const uint16_t*)yb, W1P, b1, cw, S, b0);
  }

  k_final<<<cdiv(N_BATCH * DIM, 256), 256, 0, stream>>>(S, W2, b2, out);
}

// Round 16
// 481.216 us; speedup vs baseline: 1.4022x; 1.0918x over previous
//
#include <hip/hip_runtime.h>
#include <stdint.h>

#define N_NODES 20000
#define N_EDGES 320000
#define N_BATCH 32
#define DIM     128

typedef _Float16 v8h __attribute__((ext_vector_type(8)));
typedef float v4f __attribute__((ext_vector_type(4)));
typedef float f4v __attribute__((ext_vector_type(4)));      // native vec for nontemporal
typedef unsigned int u4v __attribute__((ext_vector_type(4)));

static inline int cdiv(int a, int b){ return (a + b - 1) / b; }

// pack two f32 -> two f16 (RTZ), single v_cvt_pkrtz_f16_f32 (GCN-era instr)
__device__ __forceinline__ uint32_t pk_f16(float lo, float hi){
  auto h = __builtin_amdgcn_cvt_pkrtz(lo, hi);   // __fp16 ext_vector(2)
  return __builtin_bit_cast(uint32_t, h);
}
// acc += f32(f16 from lo/hi half of u) * w  -- single v_fma_mix_f32 (gfx906+)
__device__ __forceinline__ void fmix_lo(float& acc, uint32_t u, float w){
  asm("v_fma_mix_f32 %0, %1, %2, %0 op_sel:[0,0,0] op_sel_hi:[1,0,0]"
      : "+v"(acc) : "v"(u), "v"(w));
}
__device__ __forceinline__ void fmix_hi(float& acc, uint32_t u, float w){
  asm("v_fma_mix_f32 %0, %1, %2, %0 op_sel:[1,0,0] op_sel_hi:[1,0,0]"
      : "+v"(acc) : "v"(u), "v"(w));
}

// ---------------- setup kernels ----------------

__global__ void k_zero(uint32_t* p, int n){
  int i = blockIdx.x * 256 + threadIdx.x;
  if (i < n) p[i] = 0u;
}

__global__ void k_hist(const int* __restrict__ ei, uint32_t* __restrict__ hist){
  int e = blockIdx.x * 256 + threadIdx.x;
  if (e < N_EDGES){
    int d = ei[N_EDGES + e];
    atomicAdd(&hist[d], 1u);
  }
}

// single-block exclusive scan of hist -> row_start; also deg-derived dinv, c-init
__global__ void k_scan(const uint32_t* __restrict__ hist, uint32_t* __restrict__ row_start,
                       float* __restrict__ dinv, float* __restrict__ cw){
  __shared__ uint32_t part[1024];
  const int t = threadIdx.x;
  const int base = t * 20;                       // 1024*20 = 20480 >= 20000
  uint32_t cnt[20];
  uint32_t s = 0;
  #pragma unroll
  for (int i = 0; i < 20; i++){
    int idx = base + i;
    uint32_t v = (idx < N_NODES) ? hist[idx] : 0u;
    cnt[i] = v; s += v;
  }
  part[t] = s;
  __syncthreads();
  for (int off = 1; off < 1024; off <<= 1){      // inclusive Hillis-Steele
    uint32_t v = part[t];
    uint32_t add = (t >= off) ? part[t - off] : 0u;
    __syncthreads();
    part[t] = v + add;
    __syncthreads();
  }
  uint32_t run = (t > 0) ? part[t - 1] : 0u;     // exclusive prefix
  #pragma unroll
  for (int i = 0; i < 20; i++){
    int idx = base + i;
    if (idx < N_NODES){
      row_start[idx] = run;
      float deg = (float)cnt[i] + 1.0f;
      dinv[idx] = rsqrtf(deg);
      cw[idx]   = 1.0f / deg;                    // self_norm; edge terms added by k_edge
      run += cnt[i];
    }
  }
}

// emeta.x = src * 256 (byte offset of src row in a batch slab), emeta.y = f32 weight bits
__global__ void k_edge(const int* __restrict__ ei, const uint32_t* __restrict__ row_start,
                       uint32_t* __restrict__ cursor, const float* __restrict__ dinv,
                       float* __restrict__ cw, int2* __restrict__ emeta){
  int e = blockIdx.x * 256 + threadIdx.x;
  if (e >= N_EDGES) return;
  int s = ei[e];
  int d = ei[N_EDGES + e];
  float w = dinv[s] * dinv[d];
  atomicAdd(&cw[s], w);
  uint32_t off = atomicAdd(&cursor[d], 1u);
  uint32_t pos = row_start[d] + off;
  emeta[pos] = make_int2(s << 8, __float_as_int(w));
}

// W1 fp32 [k][f] -> f16 frag-packed: W1P[((k>>3)*128 + f)*8 + (k&7)]
__global__ void k_w1pack(const float* __restrict__ W1, uint16_t* __restrict__ W1P){
  int i = blockIdx.x * 256 + threadIdx.x;
  if (i >= 16 * 128 * 8) return;
  int e = i & 7, f = (i >> 3) & 127, q = i >> 10;
  int k = q * 8 + e;
  W1P[i] = (uint16_t)(pk_f16(W1[k * 128 + f], 0.0f) & 0xffffu);
}

// fp32 -> packed f16: 32B read / 16B write per lane, cvt_pkrtz pack, grid-stride.
// gene is read exactly once -> non-temporal loads (don't evict xb being written).
__global__ void k_cvt(const f4v* __restrict__ x, uint4* __restrict__ xb, int n_u4){
  int i = blockIdx.x * 256 + threadIdx.x;
  int stride = gridDim.x * 256;
  for (; i < n_u4; i += stride){
    f4v f0 = __builtin_nontemporal_load(&x[2 * i]);
    f4v f1 = __builtin_nontemporal_load(&x[2 * i + 1]);
    uint4 o;
    o.x = pk_f16(f0.x, f0.y);
    o.y = pk_f16(f0.z, f0.w);
    o.z = pk_f16(f1.x, f1.y);
    o.w = pk_f16(f1.z, f1.w);
    xb[i] = o;
  }
}

// ---------------- phase A: y = (A_hat x), f16 in/out, fp32 accum ----------------
// R9 champion structure, unchanged: one wave per (dst node, batch); dwordx4 gathers,
// 16 lanes cover one 256B feature row, 4 lane-groups each handle a DIFFERENT edge
// (4 edges per wave-load); 64-edge meta prefetch + bpermute broadcast; 4-deep static
// pipeline (16 edges / 4KB in flight); v_fma_mix_f32 consume (1 instr/feature).
// R16 delta: yb stored NON-TEMPORALLY -- the 164MB write-once stream no longer
// allocates L2/L3 lines, so it stops evicting the 5.12MB xb gather slab.
__global__ __launch_bounds__(256) void k_agg(const uint32_t* __restrict__ xb, uint32_t* __restrict__ yb,
                      const int2* __restrict__ emeta, const uint32_t* __restrict__ row_start,
                      const uint32_t* __restrict__ hist, const float* __restrict__ dinv){
  const int wv = threadIdx.x >> 6, lane = threadIdx.x & 63;
  const int g = lane >> 4, s = lane & 15;
  int n = blockIdx.x * 4 + wv;
  if (n >= N_NODES) return;
  const uint32_t bl = blockIdx.y;
  const char* xbase = (const char*)xb + (size_t)bl * ((size_t)N_NODES * 256);
  const uint32_t s16 = (uint32_t)s * 16u;

  float a0=0.f, a1=0.f, a2=0.f, a3=0.f, a4=0.f, a5=0.f, a6=0.f, a7=0.f;

#define CONS(VV, WW) do { \
    fmix_lo(a0, (VV).x, (WW)); fmix_hi(a1, (VV).x, (WW)); \
    fmix_lo(a2, (VV).y, (WW)); fmix_hi(a3, (VV).y, (WW)); \
    fmix_lo(a4, (VV).z, (WW)); fmix_hi(a5, (VV).z, (WW)); \
    fmix_lo(a6, (VV).w, (WW)); fmix_hi(a7, (VV).w, (WW)); \
  } while(0)

#define PREP(P, VV, WW) do { \
    uint32_t idx_ = sbase + (P)*4u + (uint32_t)g; \
    uint32_t ci_  = (idx_ < lim) ? idx_ : (lim - 1u); \
    uint32_t so_  = (uint32_t)__shfl(mx, (int)ci_); \
    float    wf_  = __int_as_float(__shfl(my, (int)ci_)); \
    WW = (idx_ < lim) ? wf_ : 0.0f; \
    VV = *reinterpret_cast<const uint4*>(xbase + (so_ + s16)); \
  } while(0)

  // self term: all 4 groups load the same row (HW broadcasts), weight self/4
  float di = dinv[n];
  {
    uint4 sv = *reinterpret_cast<const uint4*>(xbase + ((uint32_t)n * 256u + s16));
    float wself = di * di * 0.25f;
    CONS(sv, wself);
  }

  uint32_t rs  = (uint32_t)__builtin_amdgcn_readfirstlane((int)row_start[n]);
  uint32_t cnt = (uint32_t)__builtin_amdgcn_readfirstlane((int)hist[n]);

  for (uint32_t cbase = 0; cbase < cnt; cbase += 64u){
    uint32_t lim = cnt - cbase; if (lim > 64u) lim = 64u;   // edges in this chunk, >=1
    uint32_t cl = (uint32_t)lane; if (cl >= lim) cl = lim - 1u;
    int2 m = emeta[rs + cbase + cl];                        // one coalesced 512B load
    int mx = m.x, my = m.y;

    uint32_t sbase = 0;
    while (sbase + 16u <= lim){                             // full 16-edge super-steps
      uint4 p0, p1, p2, p3; float q0, q1, q2, q3;
      PREP(0, p0, q0); PREP(1, p1, q1); PREP(2, p2, q2); PREP(3, p3, q3);
      CONS(p0, q0); CONS(p1, q1); CONS(p2, q2); CONS(p3, q3);
      sbase += 16u;
    }
    if (sbase < lim){                                       // tail: 1..15 edges
      uint32_t live = lim - sbase;
      uint4 p0, p1, p2, p3; float q0, q1, q2, q3;
      PREP(0, p0, q0);
      if (live > 4u)  { PREP(1, p1, q1); }
      if (live > 8u)  { PREP(2, p2, q2); }
      if (live > 12u) { PREP(3, p3, q3); }
      CONS(p0, q0);
      if (live > 4u)  { CONS(p1, q1); }
      if (live > 8u)  { CONS(p2, q2); }
      if (live > 12u) { CONS(p3, q3); }
    }
  }
#undef PREP
#undef CONS

  // reduce over the 4 edge-groups: lanes {s, s+16, s+32, s+48} hold same features
  a0 += __shfl_xor(a0, 16); a0 += __shfl_xor(a0, 32);
  a1 += __shfl_xor(a1, 16); a1 += __shfl_xor(a1, 32);
  a2 += __shfl_xor(a2, 16); a2 += __shfl_xor(a2, 32);
  a3 += __shfl_xor(a3, 16); a3 += __shfl_xor(a3, 32);
  a4 += __shfl_xor(a4, 16); a4 += __shfl_xor(a4, 32);
  a5 += __shfl_xor(a5, 16); a5 += __shfl_xor(a5, 32);
  a6 += __shfl_xor(a6, 16); a6 += __shfl_xor(a6, 32);
  a7 += __shfl_xor(a7, 16); a7 += __shfl_xor(a7, 32);

  if (lane < 16){
    u4v o;
    o.x = pk_f16(a0, a1);
    o.y = pk_f16(a2, a3);
    o.z = pk_f16(a4, a5);
    o.w = pk_f16(a6, a7);
    char* ybase = (char*)yb + (size_t)bl * ((size_t)N_NODES * 256);
    __builtin_nontemporal_store(o, reinterpret_cast<u4v*>(ybase + ((uint32_t)n * 256u + s16)));
  }
}

// ---------------- phase B: S[b,f] += sum_n c[n]*relu(y[b,n,:]·W1[:,f] + b1[f]) ----------------
// 4 waves/block; each wave: W1 fully in registers (32 B-frags), loops 8 n-tiles of 16 rows.
// yb is read exactly once -> non-temporal loads.
__global__ __launch_bounds__(256) void k_gemm(const uint16_t* __restrict__ y,
                                              const uint16_t* __restrict__ W1P,
                                              const float* __restrict__ b1,
                                              const float* __restrict__ cw,
                                              float* __restrict__ S, int b_global0){
  const int w = threadIdx.x >> 6, lane = threadIdx.x & 63;
  const int l15 = lane & 15, q = lane >> 4;
  const int bl = blockIdx.y;

  // B-frags: lane l, elem e -> W1[k][ft*16 + l15], k = q32*32 + q*8 + e  (same k-map as A)
  v8h bfr[4][8];
  #pragma unroll
  for (int q32 = 0; q32 < 4; q32++)
    #pragma unroll
    for (int ft = 0; ft < 8; ft++)
      bfr[q32][ft] = *reinterpret_cast<const v8h*>(W1P + ((q32 * 4 + q) * 128 + ft * 16 + l15) * 8);

  float b1v[8];
  #pragma unroll
  for (int ft = 0; ft < 8; ft++) b1v[ft] = b1[ft * 16 + l15];

  float sacc[8] = {0.f,0.f,0.f,0.f,0.f,0.f,0.f,0.f};

  const int NT = N_NODES / 16;                   // 1250 full tiles
  int tile0 = (blockIdx.x * 4 + w) * 8;
  for (int t = 0; t < 8; t++){
    int tile = tile0 + t;
    if (tile >= NT) break;
    int n0 = tile * 16;
    const uint16_t* yrow = y + ((size_t)bl * N_NODES + n0 + l15) * DIM + q * 8;
    v8h a0 = __builtin_nontemporal_load(reinterpret_cast<const v8h*>(yrow));
    v8h a1 = __builtin_nontemporal_load(reinterpret_cast<const v8h*>(yrow + 32));
    v8h a2 = __builtin_nontemporal_load(reinterpret_cast<const v8h*>(yrow + 64));
    v8h a3 = __builtin_nontemporal_load(reinterpret_cast<const v8h*>(yrow + 96));

    v4f acc[8];
    #pragma unroll
    for (int ft = 0; ft < 8; ft++) acc[ft] = (v4f){0.f,0.f,0.f,0.f};
    #pragma unroll
    for (int ft = 0; ft < 8; ft++) acc[ft] = __builtin_amdgcn_mfma_f32_16x16x32_f16(a0, bfr[0][ft], acc[ft], 0, 0, 0);
    #pragma unroll
    for (int ft = 0; ft < 8; ft++) acc[ft] = __builtin_amdgcn_mfma_f32_16x16x32_f16(a1, bfr[1][ft], acc[ft], 0, 0, 0);
    #pragma unroll
    for (int ft = 0; ft < 8; ft++) acc[ft] = __builtin_amdgcn_mfma_f32_16x16x32_f16(a2, bfr[2][ft], acc[ft], 0, 0, 0);
    #pragma unroll
    for (int ft = 0; ft < 8; ft++) acc[ft] = __builtin_amdgcn_mfma_f32_16x16x32_f16(a3, bfr[3][ft], acc[ft], 0, 0, 0);

    // epilogue: + b1, relu, * c[row], accumulate. D: row = n0 + q*4 + r, col = ft*16 + l15
    float4 cvv = *reinterpret_cast<const float4*>(cw + n0 + q * 4);
    float cvr[4] = {cvv.x, cvv.y, cvv.z, cvv.w};
    #pragma unroll
    for (int ft = 0; ft < 8; ft++){
      #pragma unroll
      for (int r = 0; r < 4; r++){
        float v = acc[ft][r] + b1v[ft];
        v = fmaxf(v, 0.0f);
        sacc[ft] = fmaf(v, cvr[r], sacc[ft]);
      }
    }
  }

  // reduce over q-groups (rows) -> col sums, then one atomic per (f)
  #pragma unroll
  for (int ft = 0; ft < 8; ft++){
    float v = sacc[ft];
    v += __shfl_xor(v, 16);
    v += __shfl_xor(v, 32);
    if (lane < 16) atomicAdd(&S[(b_global0 + bl) * DIM + ft * 16 + lane], v);
  }
}

// ---------------- final: out[b,f] = (S[b,:]/N)·W2[:,f] + b2[f] ----------------
__global__ void k_final(const float* __restrict__ S, const float* __restrict__ W2,
                        const float* __restrict__ b2, float* __restrict__ out){
  int i = blockIdx.x * 256 + threadIdx.x;
  if (i >= N_BATCH * DIM) return;
  int b = i >> 7, f = i & 127;
  float o = 0.0f;
  const float invN = 1.0f / (float)N_NODES;
  #pragma unroll 4
  for (int k = 0; k < 128; k++)
    o = fmaf(S[b * 128 + k], W2[k * 128 + f], o);
  out[i] = fmaf(o, invN, b2[f]);
}

// ---------------- host ----------------

extern "C" void kernel_launch(void* const* d_in, const int* in_sizes, int n_in,
                              void* d_out, int out_size, void* d_ws, size_t ws_size,
                              hipStream_t stream){
  const float* gene = (const float*)d_in[0];
  const int*   ei   = (const int*)d_in[1];
  const float* W1   = (const float*)d_in[2];
  const float* b1   = (const float*)d_in[3];
  const float* W2   = (const float*)d_in[4];
  const float* b2   = (const float*)d_in[5];
  float* out = (float*)d_out;

  char* base = (char*)d_ws;
  size_t off = 0;
  auto take = [&](size_t bytes)->char*{
    char* p = base + off;
    off = (off + bytes + 255) & ~(size_t)255;
    return p;
  };

  // zero zone: hist (N+1) | cursor (N) | S (B*128 f32)  -- one contiguous zero pass
  const int ZWORDS = (N_NODES + 1) + N_NODES + N_BATCH * DIM;
  uint32_t* zzone  = (uint32_t*)take((size_t)ZWORDS * 4);
  uint32_t* hist   = zzone;
  uint32_t* cursor = zzone + (N_NODES + 1);
  float*    S      = (float*)(zzone + (N_NODES + 1) + N_NODES);

  uint32_t* row_start = (uint32_t*)take((size_t)N_NODES * 4);
  float*    dinv      = (float*)take((size_t)N_NODES * 4);
  float*    cw        = (float*)take((size_t)N_NODES * 4);
  int2*     emeta     = (int2*)take((size_t)N_EDGES * 8);
  uint16_t* W1P       = (uint16_t*)take((size_t)16 * 128 * 8 * 2);

  // batch-chunked x/y f16 buffers sized to fit ws (R9 behavior: C up to 32)
  const size_t per_batch = (size_t)N_NODES * DIM * 2;   // 5.12 MB
  size_t remain = (ws_size > off) ? (ws_size - off) : 0;
  int C = (int)(remain / (2 * per_batch));
  if (C < 1) C = 1;
  if (C > N_BATCH) C = N_BATCH;
  uint32_t* xb = (uint32_t*)take(per_batch * C);
  uint32_t* yb = (uint32_t*)take(per_batch * C);

  k_zero<<<cdiv(ZWORDS, 256), 256, 0, stream>>>(zzone, ZWORDS);
  k_hist<<<cdiv(N_EDGES, 256), 256, 0, stream>>>(ei, hist);
  k_scan<<<1, 1024, 0, stream>>>(hist, row_start, dinv, cw);
  k_edge<<<cdiv(N_EDGES, 256), 256, 0, stream>>>(ei, row_start, cursor, dinv, cw, emeta);
  k_w1pack<<<64, 256, 0, stream>>>(W1, W1P);

  for (int b0 = 0; b0 < N_BATCH; b0 += C){
    int Cb = (N_BATCH - b0 < C) ? (N_BATCH - b0) : C;
    int nu4 = Cb * N_NODES * (DIM / 8);
    int cvtb = cdiv(nu4, 256 * 8); if (cvtb > 2048) cvtb = 2048;
    k_cvt<<<cvtb, 256, 0, stream>>>(((const f4v*)gene) + (size_t)b0 * N_NODES * (DIM / 4),
                                    (uint4*)xb, nu4);
    k_agg<<<dim3(N_NODES / 4, Cb), 256, 0, stream>>>(xb, yb, emeta, row_start, hist, dinv);
    k_gemm<<<dim3(cdiv(N_NODES / 16, 32), Cb), 256, 0, stream>>>((const uint16_t*)yb, W1P, b1, cw, S, b0);
  }

  k_final<<<cdiv(N_BATCH * DIM, 256), 256, 0, stream>>>(S, W2, b2, out);
}